// Round 6
// baseline (360.257 us; speedup 1.0000x reference)
//
#include <hip/hip_runtime.h>

#define B_ROWS 16384
#define C_DIM  2048
#define BLK    512               // 8 waves
#define NWAVE  (BLK / 64)
#define RPW    2                 // rows per wave
#define RPB    (NWAVE * RPW)     // 16 rows per block -> grid.x = 1024, grid.y = 3
#define NACC   5                 // aff0, aff1, aff2, cls0, cls1
#define NCHUNK (C_DIM / 256)     // 8 chunks of 64 lanes x 4 cols

typedef float f32x4 __attribute__((ext_vector_type(4)));

#define DPP_ADD(v, ctrl, rmask) \
  v += __int_as_float(__builtin_amdgcn_update_dpp(0, __float_as_int(v), (ctrl), (rmask), 0xf, false))

// Inline-asm global load with EARLY-CLOBBER dest: forces a real
// global_load_dwordx4 whose destination quad is disjoint from every live
// register (incl. the address pair). 16 back-to-back = 16 KB in flight per
// wave, guaranteed -- the compiler cannot collapse or rematerialize these.
// asm volatile statements keep program order among themselves.
#define GL(dst, base, OFF) \
  asm volatile("global_load_dwordx4 %0, %1, off offset:" OFF \
               : "=&v"(dst) : "v"(base))

// Per-chunk drain: weight ds_reads issue BEFORE the vmcnt (their latency
// hides under the drain), then staged vmcnt + sched_barrier(0) (rule #18:
// register-only FMAs would otherwise hoist above a bare asm waitcnt).
#define CHUNK(CH, VM, X0, X1) do {                                          \
    f32x4 w0 = wp[0 * BLK + CH * 64];                                       \
    f32x4 w1 = wp[1 * BLK + CH * 64];                                       \
    f32x4 w2 = wp[2 * BLK + CH * 64];                                       \
    f32x4 w3 = wp[3 * BLK + CH * 64];                                       \
    f32x4 w4 = wp[4 * BLK + CH * 64];                                       \
    asm volatile("s_waitcnt vmcnt(" VM ")" ::: "memory");                   \
    __builtin_amdgcn_sched_barrier(0);                                      \
    acc00 = fmaf(X0.w,w0.w,fmaf(X0.z,w0.z,fmaf(X0.y,w0.y,fmaf(X0.x,w0.x,acc00)))); \
    acc01 = fmaf(X0.w,w1.w,fmaf(X0.z,w1.z,fmaf(X0.y,w1.y,fmaf(X0.x,w1.x,acc01)))); \
    acc02 = fmaf(X0.w,w2.w,fmaf(X0.z,w2.z,fmaf(X0.y,w2.y,fmaf(X0.x,w2.x,acc02)))); \
    acc03 = fmaf(X0.w,w3.w,fmaf(X0.z,w3.z,fmaf(X0.y,w3.y,fmaf(X0.x,w3.x,acc03)))); \
    acc04 = fmaf(X0.w,w4.w,fmaf(X0.z,w4.z,fmaf(X0.y,w4.y,fmaf(X0.x,w4.x,acc04)))); \
    acc10 = fmaf(X1.w,w0.w,fmaf(X1.z,w0.z,fmaf(X1.y,w0.y,fmaf(X1.x,w0.x,acc10)))); \
    acc11 = fmaf(X1.w,w1.w,fmaf(X1.z,w1.z,fmaf(X1.y,w1.y,fmaf(X1.x,w1.x,acc11)))); \
    acc12 = fmaf(X1.w,w2.w,fmaf(X1.z,w2.z,fmaf(X1.y,w2.y,fmaf(X1.x,w2.x,acc12)))); \
    acc13 = fmaf(X1.w,w3.w,fmaf(X1.z,w3.z,fmaf(X1.y,w3.y,fmaf(X1.x,w3.x,acc13)))); \
    acc14 = fmaf(X1.w,w4.w,fmaf(X1.z,w4.z,fmaf(X1.y,w4.y,fmaf(X1.x,w4.x,acc14)))); \
  } while (0)

__global__ __launch_bounds__(BLK, 4)
void maff_partial(const float* __restrict__ s_f,
                  const float* __restrict__ g_f,
                  const float* __restrict__ v_f,
                  const float* __restrict__ W_aff,
                  const float* __restrict__ W_cls,
                  float* __restrict__ ws)
{
  const int t    = threadIdx.x;
  const int lane = t & 63;
  const int wave = t >> 6;
  const int m    = blockIdx.y;
  const int row0 = blockIdx.x * RPB + wave * RPW;

  const float* f = (m == 0) ? s_f : (m == 1) ? g_f : v_f;

  // ---- LDS weights: W[j][quad] = weights of output j for column quad ----
  __shared__ f32x4 W[NACC][BLK];   // 40 KB
  {
    const f32x4* pa = (const f32x4*)(W_aff + ((size_t)m * C_DIM + t * 4) * 3);
    f32x4 a0 = pa[0], a1 = pa[1], a2 = pa[2];
    const f32x4* pc = (const f32x4*)(W_cls + ((size_t)m * C_DIM + t * 4) * 2);
    f32x4 q0 = pc[0], q1 = pc[1];
    W[0][t] = (f32x4){a0.x, a0.w, a1.z, a2.y};   // aff col 0
    W[1][t] = (f32x4){a0.y, a1.x, a1.w, a2.z};   // aff col 1
    W[2][t] = (f32x4){a0.z, a1.y, a2.x, a2.w};   // aff col 2
    W[3][t] = (f32x4){q0.x, q0.z, q1.x, q1.z};   // cls col 0
    W[4][t] = (f32x4){q0.y, q0.w, q1.y, q1.w};   // cls col 1
  }
  __syncthreads();

  // 4 address bases (13-bit signed imm offset -> split each row in half)
  const float* pA0 = f + (size_t)row0 * C_DIM + lane * 4;  // row0 chunks 0..3
  const float* pA4 = pA0 + 1024;                           // row0 chunks 4..7
  const float* pB0 = pA0 + C_DIM;                          // row1 chunks 0..3
  const float* pB4 = pB0 + 1024;                           // row1 chunks 4..7

  // ---- issue ALL 16 loads back-to-back (chunk-major = drain order) ----
  f32x4 x00, x10, x01, x11, x02, x12, x03, x13;
  f32x4 x04, x14, x05, x15, x06, x16, x07, x17;
  GL(x00, pA0, "0");    GL(x10, pB0, "0");
  GL(x01, pA0, "1024"); GL(x11, pB0, "1024");
  GL(x02, pA0, "2048"); GL(x12, pB0, "2048");
  GL(x03, pA0, "3072"); GL(x13, pB0, "3072");
  GL(x04, pA4, "0");    GL(x14, pB4, "0");
  GL(x05, pA4, "1024"); GL(x15, pB4, "1024");
  GL(x06, pA4, "2048"); GL(x16, pB4, "2048");
  GL(x07, pA4, "3072"); GL(x17, pB4, "3072");

  const f32x4* wp = (const f32x4*)&W[0][lane];

  float acc00 = 0.f, acc01 = 0.f, acc02 = 0.f, acc03 = 0.f, acc04 = 0.f;
  float acc10 = 0.f, acc11 = 0.f, acc12 = 0.f, acc13 = 0.f, acc14 = 0.f;

  // ---- staged drain: chunk k computes once loads 2k,2k+1 have landed ----
  CHUNK(0, "14", x00, x10);
  CHUNK(1, "12", x01, x11);
  CHUNK(2, "10", x02, x12);
  CHUNK(3, "8",  x03, x13);
  CHUNK(4, "6",  x04, x14);
  CHUNK(5, "4",  x05, x15);
  CHUNK(6, "2",  x06, x16);
  CHUNK(7, "0",  x07, x17);

  // ---- one full-wave reduction per row (6 DPP steps per accumulator) ----
  float accs[RPW][NACC] = {{acc00, acc01, acc02, acc03, acc04},
                           {acc10, acc11, acc12, acc13, acc14}};
#pragma unroll
  for (int r = 0; r < RPW; ++r)
#pragma unroll
    for (int j = 0; j < NACC; ++j) {
      float v = accs[r][j];
      DPP_ADD(v, 0x111, 0xf);   // row_shr:1
      DPP_ADD(v, 0x112, 0xf);   // row_shr:2
      DPP_ADD(v, 0x114, 0xf);   // row_shr:4
      DPP_ADD(v, 0x118, 0xf);   // row_shr:8  -> lane 16k+15 = group sum
      DPP_ADD(v, 0x142, 0xa);   // row_bcast:15
      DPP_ADD(v, 0x143, 0xc);   // row_bcast:31 -> lane 63 = full wave sum
      accs[r][j] = v;
    }

  if (lane == 63) {
#pragma unroll
    for (int r = 0; r < RPW; ++r)
#pragma unroll
      for (int j = 0; j < NACC; ++j)
        ws[(size_t)(m * NACC + j) * B_ROWS + row0 + r] = accs[r][j];
  }
}

// Kernel 2: per-row epilogue. 15 coalesced reads, two softmaxes, float2 store.
__global__ __launch_bounds__(256)
void maff_epilogue(const float* __restrict__ ws,
                   const float* __restrict__ b_aff,
                   const float* __restrict__ b_cls,
                   float* __restrict__ out)
{
  const int row = blockIdx.x * 256 + threadIdx.x;

  float P[3][NACC];
#pragma unroll
  for (int m = 0; m < 3; ++m)
#pragma unroll
    for (int j = 0; j < NACC; ++j)
      P[m][j] = ws[(m * NACC + j) * B_ROWS + row];

  float A0 = P[0][0] + P[1][0] + P[2][0] + b_aff[0];
  float A1 = P[0][1] + P[1][1] + P[2][1] + b_aff[1];
  float A2 = P[0][2] + P[1][2] + P[2][2] + b_aff[2];

  float mx = fmaxf(A0, fmaxf(A1, A2));
  float e0 = __expf(A0 - mx), e1 = __expf(A1 - mx), e2 = __expf(A2 - mx);
  float inv = 1.0f / (e0 + e1 + e2);
  float t0 = e0 * inv, t1 = e1 * inv, t2 = e2 * inv;

  float L0 = t0 * P[0][3] + t1 * P[1][3] + t2 * P[2][3] + b_cls[0];
  float L1 = t0 * P[0][4] + t1 * P[1][4] + t2 * P[2][4] + b_cls[1];
  float mm = fmaxf(L0, L1);
  float x0 = __expf(L0 - mm), x1 = __expf(L1 - mm);
  float is = 1.0f / (x0 + x1);

  *(float2*)(out + (size_t)row * 2) = make_float2(x0 * is, x1 * is);
}

extern "C" void kernel_launch(void* const* d_in, const int* in_sizes, int n_in,
                              void* d_out, int out_size, void* d_ws, size_t ws_size,
                              hipStream_t stream) {
  const float* s_f   = (const float*)d_in[0];
  const float* g_f   = (const float*)d_in[1];
  const float* v_f   = (const float*)d_in[2];
  const float* W_aff = (const float*)d_in[3];
  const float* b_aff = (const float*)d_in[4];
  const float* W_cls = (const float*)d_in[5];
  const float* b_cls = (const float*)d_in[6];
  float* out = (float*)d_out;
  float* ws  = (float*)d_ws;   // 15 * B * 4 = 983 KB

  dim3 grid1(B_ROWS / RPB, 3);   // 1024 x 3 = 3072 blocks, 512 thr each
  maff_partial<<<grid1, dim3(BLK), 0, stream>>>(s_f, g_f, v_f, W_aff, W_cls, ws);

  dim3 grid2(B_ROWS / 256);      // 64 blocks
  maff_epilogue<<<grid2, dim3(256), 0, stream>>>(ws, b_aff, b_cls, out);
}